// Round 1
// baseline (527.197 us; speedup 1.0000x reference)
//
#include <hip/hip_runtime.h>
#include <hip/hip_bf16.h>

// Problem constants
#define NB   32
#define CCH  128
#define HH   64
#define WW   64
#define DBOT 512
#define EPS_LN 1e-5f

typedef __attribute__((ext_vector_type(8))) short bf16x8;
typedef __attribute__((ext_vector_type(4))) float f32x4;

// ---------------------------------------------------------------------------
// K0: convert pointwise weights fp32 -> bf16 into workspace
// ---------------------------------------------------------------------------
__global__ __launch_bounds__(256) void wcvt_kernel(
    const float* __restrict__ w1, const float* __restrict__ w2,
    __hip_bfloat16* __restrict__ o1, __hip_bfloat16* __restrict__ o2)
{
    int i = blockIdx.x * 256 + threadIdx.x;   // 0 .. 65535
    o1[i] = __float2bfloat16(w1[i]);
    o2[i] = __float2bfloat16(w2[i]);
}

// ---------------------------------------------------------------------------
// K1: depthwise 7x7 conv + bias + channel LayerNorm -> y_norm (NHWC, bf16)
// one block per (n, h): computes all 128 c x 64 w outputs of that row
// ---------------------------------------------------------------------------
__global__ __launch_bounds__(256) void conv_ln_kernel(
    const float* __restrict__ x, const float* __restrict__ dw_w,
    const float* __restrict__ dw_b, const float* __restrict__ gamma,
    const float* __restrict__ beta, __hip_bfloat16* __restrict__ ynorm)
{
    __shared__ float sConv[CCH * 68];   // [c][w], stride 68 to break bank conflicts
    __shared__ float sPart[2][4 * 64];  // partial sums / sumsq
    __shared__ float sMu[64], sRstd[64];

    const int t  = threadIdx.x;
    const int n  = blockIdx.x >> 6;
    const int h  = blockIdx.x & 63;
    const int w  = t & 63;
    const int cg = t >> 6;              // 0..3

    for (int i = 0; i < 32; ++i) {
        const int c = i * 4 + cg;
        const float* wp = dw_w + c * 49;
        float wgt[49];
        #pragma unroll
        for (int j = 0; j < 49; ++j) wgt[j] = wp[j];
        float acc = dw_b[c];
        const float* xc = x + ((size_t)(n * CCH + c) << 12);
        #pragma unroll
        for (int kh = 0; kh < 7; ++kh) {
            int hh = h + kh - 3;
            if (hh < 0 || hh >= HH) continue;       // block-uniform branch
            const float* xrow = xc + (hh << 6);
            #pragma unroll
            for (int kw = 0; kw < 7; ++kw) {
                int ww = w + kw - 3;
                float xv = (ww >= 0 && ww < WW) ? xrow[ww] : 0.0f;
                acc = fmaf(xv, wgt[kh * 7 + kw], acc);
            }
        }
        sConv[c * 68 + w] = acc;
    }
    __syncthreads();

    // LayerNorm stats over c (128) per w
    float s = 0.f, s2 = 0.f;
    for (int j = 0; j < 32; ++j) {
        float v = sConv[(cg * 32 + j) * 68 + w];
        s += v;
        s2 = fmaf(v, v, s2);
    }
    sPart[0][cg * 64 + w] = s;
    sPart[1][cg * 64 + w] = s2;
    __syncthreads();
    if (t < 64) {
        float su = 0.f, sq = 0.f;
        #pragma unroll
        for (int g = 0; g < 4; ++g) { su += sPart[0][g * 64 + t]; sq += sPart[1][g * 64 + t]; }
        float mu  = su * (1.0f / 128.0f);
        float var = sq * (1.0f / 128.0f) - mu * mu;
        sMu[t]   = mu;
        sRstd[t] = 1.0f / sqrtf(var + EPS_LN);
    }
    __syncthreads();

    // normalize + write NHWC bf16 (c contiguous)
    __hip_bfloat16* yo = ynorm + (size_t)blockIdx.x * 64 * CCH;
    for (int i = 0; i < 32; ++i) {
        int linear = i * 256 + t;
        int c  = linear & 127;
        int wi = linear >> 7;
        float v = sConv[c * 68 + wi];
        float r = (v - sMu[wi]) * sRstd[wi] * gamma[c] + beta[c];
        yo[wi * CCH + c] = __float2bfloat16(r);
    }
}

// ---------------------------------------------------------------------------
// K2: fused pointwise MLP (bf16 MFMA) + bias + residual, NCHW output
// one block per 64-row M tile (= one (n,h) row, w = 0..63)
// ---------------------------------------------------------------------------
#define YS 136   // bf16 row stride for sY/sH (272 B: 16B-aligned, 2-way-bank only)
#define OS 65    // float row stride for sO

__global__ __launch_bounds__(256) void mlp_kernel(
    const __hip_bfloat16* __restrict__ yn,   // M x 128 (bf16)
    const __hip_bfloat16* __restrict__ w1,   // 512 x 128 (bf16)
    const float* __restrict__ b1,            // 512
    const __hip_bfloat16* __restrict__ w2,   // 128 x 512 (bf16)
    const float* __restrict__ b2,            // 128
    const float* __restrict__ x,             // NCHW fp32
    float* __restrict__ out)                 // NCHW fp32
{
    __shared__ union {
        struct { unsigned short y[64 * YS]; unsigned short h[64 * YS]; } s;
        float o[CCH * OS];
    } u;

    const int t    = threadIdx.x;
    const int wave = t >> 6;
    const int lane = t & 63;
    const int q    = lane >> 4;          // 0..3
    const int ln   = lane & 15;          // 0..15
    const int wm   = (wave >> 1) * 32;   // wave M offset (0/32)
    const int wn   = (wave & 1) * 64;    // wave N offset (0/64)

    const size_t m0 = (size_t)blockIdx.x * 64;

    // stage y tile (64 x 128 bf16) into LDS, coalesced 16B loads
    {
        const uint4* src = (const uint4*)(yn + m0 * CCH);
        int row = t >> 4, chunk = t & 15;
        #pragma unroll
        for (int it = 0; it < 4; ++it) {
            uint4 v = src[(size_t)(row + it * 16) * 16 + chunk];
            *(uint4*)&u.s.y[(row + it * 16) * YS + chunk * 8] = v;
        }
    }

    f32x4 oacc[2][4];
    #pragma unroll
    for (int mt = 0; mt < 2; ++mt)
        #pragma unroll
        for (int ct = 0; ct < 4; ++ct) oacc[mt][ct] = (f32x4){0.f, 0.f, 0.f, 0.f};

    __syncthreads();

    for (int dc = 0; dc < 4; ++dc) {
        const int d0 = dc * 128;
        f32x4 hacc[2][4];
        #pragma unroll
        for (int mt = 0; mt < 2; ++mt)
            #pragma unroll
            for (int dt = 0; dt < 4; ++dt) hacc[mt][dt] = (f32x4){0.f, 0.f, 0.f, 0.f};

        // stage 1: H = y @ W1^T for this 128-wide d chunk
        #pragma unroll
        for (int k0 = 0; k0 < 128; k0 += 32) {
            bf16x8 af[2];
            #pragma unroll
            for (int mt = 0; mt < 2; ++mt)
                af[mt] = *(const bf16x8*)&u.s.y[(wm + mt * 16 + ln) * YS + k0 + q * 8];
            bf16x8 bw[4];
            #pragma unroll
            for (int dt = 0; dt < 4; ++dt) {
                int d = d0 + wn + dt * 16 + ln;
                bw[dt] = *(const bf16x8*)(w1 + (size_t)d * 128 + k0 + q * 8);
            }
            #pragma unroll
            for (int mt = 0; mt < 2; ++mt)
                #pragma unroll
                for (int dt = 0; dt < 4; ++dt)
                    hacc[mt][dt] = __builtin_amdgcn_mfma_f32_16x16x32_bf16(
                        af[mt], bw[dt], hacc[mt][dt], 0, 0, 0);
        }

        __syncthreads();   // previous chunk's sH readers done before overwrite

        // bias + relu + bf16 -> sH (C-layout scatter)
        #pragma unroll
        for (int mt = 0; mt < 2; ++mt) {
            #pragma unroll
            for (int dt = 0; dt < 4; ++dt) {
                int dl = wn + dt * 16 + ln;
                float bv = b1[d0 + dl];
                #pragma unroll
                for (int r = 0; r < 4; ++r) {
                    float v = hacc[mt][dt][r] + bv;
                    v = fmaxf(v, 0.0f);
                    __hip_bfloat16 hb = __float2bfloat16(v);
                    u.s.h[(wm + mt * 16 + q * 4 + r) * YS + dl] = *(unsigned short*)&hb;
                }
            }
        }
        __syncthreads();

        // stage 2: O += H @ W2_chunk^T
        #pragma unroll
        for (int k0 = 0; k0 < 128; k0 += 32) {
            bf16x8 af[2];
            #pragma unroll
            for (int mt = 0; mt < 2; ++mt)
                af[mt] = *(const bf16x8*)&u.s.h[(wm + mt * 16 + ln) * YS + k0 + q * 8];
            bf16x8 bw[4];
            #pragma unroll
            for (int ct = 0; ct < 4; ++ct) {
                int c = wn + ct * 16 + ln;
                bw[ct] = *(const bf16x8*)(w2 + (size_t)c * DBOT + d0 + k0 + q * 8);
            }
            #pragma unroll
            for (int mt = 0; mt < 2; ++mt)
                #pragma unroll
                for (int ct = 0; ct < 4; ++ct)
                    oacc[mt][ct] = __builtin_amdgcn_mfma_f32_16x16x32_bf16(
                        af[mt], bw[ct], oacc[mt][ct], 0, 0, 0);
        }
    }

    __syncthreads();   // union reuse: sY/sH dead, sO live

    // O (C-layout regs) -> sO[c][w]
    #pragma unroll
    for (int mt = 0; mt < 2; ++mt) {
        #pragma unroll
        for (int ct = 0; ct < 4; ++ct) {
            int c = wn + ct * 16 + ln;
            #pragma unroll
            for (int r = 0; r < 4; ++r)
                u.o[c * OS + wm + mt * 16 + q * 4 + r] = oacc[mt][ct][r];
        }
    }
    __syncthreads();

    // epilogue: out[n,c,h,:] = sO + b2[c] + x[n,c,h,:]
    const int n = blockIdx.x >> 6;
    const int h = blockIdx.x & 63;
    const float* xb = x   + ((size_t)(n * CCH) << 12) + (h << 6);
    float*       ob = out + ((size_t)(n * CCH) << 12) + (h << 6);
    for (int i = 0; i < 32; ++i) {
        int linear = i * 256 + t;
        int c  = linear >> 6;
        int wi = linear & 63;
        float v = u.o[c * OS + wi] + b2[c] + xb[(size_t)c * 4096 + wi];
        ob[(size_t)c * 4096 + wi] = v;
    }
}

// ---------------------------------------------------------------------------
extern "C" void kernel_launch(void* const* d_in, const int* in_sizes, int n_in,
                              void* d_out, int out_size, void* d_ws, size_t ws_size,
                              hipStream_t stream)
{
    const float* x     = (const float*)d_in[0];
    const float* dw_w  = (const float*)d_in[1];
    const float* dw_b  = (const float*)d_in[2];
    const float* gamma = (const float*)d_in[3];
    const float* beta  = (const float*)d_in[4];
    const float* pw1_w = (const float*)d_in[5];
    const float* pw1_b = (const float*)d_in[6];
    const float* pw2_w = (const float*)d_in[7];
    const float* pw2_b = (const float*)d_in[8];
    float* out = (float*)d_out;

    char* ws = (char*)d_ws;
    __hip_bfloat16* ynorm = (__hip_bfloat16*)ws;                       // 32 MiB
    __hip_bfloat16* w1b   = (__hip_bfloat16*)(ws + (size_t)33554432);  // 128 KiB
    __hip_bfloat16* w2b   = (__hip_bfloat16*)(ws + (size_t)33554432 + 131072);

    wcvt_kernel<<<256, 256, 0, stream>>>(pw1_w, pw2_w, w1b, w2b);
    conv_ln_kernel<<<NB * HH, 256, 0, stream>>>(x, dw_w, dw_b, gamma, beta, ynorm);
    mlp_kernel<<<NB * HH, 256, 0, stream>>>(ynorm, w1b, pw1_b, w2b, pw2_b, x, out);
}

// Round 2
// 296.067 us; speedup vs baseline: 1.7807x; 1.7807x over previous
//
#include <hip/hip_runtime.h>
#include <hip/hip_bf16.h>

// Problem constants
#define NB   32
#define CCH  128
#define HH   64
#define WW   64
#define DBOT 512
#define EPS_LN 1e-5f

typedef __attribute__((ext_vector_type(8))) short bf16x8;
typedef __attribute__((ext_vector_type(4))) float f32x4;

// ---------------------------------------------------------------------------
// K0: convert pointwise weights fp32 -> bf16 into workspace
// ---------------------------------------------------------------------------
__global__ __launch_bounds__(256) void wcvt_kernel(
    const float* __restrict__ w1, const float* __restrict__ w2,
    __hip_bfloat16* __restrict__ o1, __hip_bfloat16* __restrict__ o2)
{
    int i = blockIdx.x * 256 + threadIdx.x;   // 0 .. 65535
    o1[i] = __float2bfloat16(w1[i]);
    o2[i] = __float2bfloat16(w2[i]);
}

// ---------------------------------------------------------------------------
// K1: depthwise 7x7 conv + bias -> conv_out (NCHW, bf16)
// one block per (n, c) plane: 64x64 outputs, 256 threads x 16 outputs
// x plane staged in LDS (float4), weights in 49 VGPRs loaded once.
// ---------------------------------------------------------------------------
#define XS 76   // LDS row stride (floats): 4 left pad + 64 data + 8 right pad

__global__ __launch_bounds__(256) void dwconv_kernel(
    const float* __restrict__ x, const float* __restrict__ dw_w,
    const float* __restrict__ dw_b, __hip_bfloat16* __restrict__ cout)
{
    __shared__ float xs[64 * XS];

    const int t = threadIdx.x;
    const int n = blockIdx.x >> 7;
    const int c = blockIdx.x & 127;

    const float* xp = x + ((size_t)(n * CCH + c) << 12);

    // stage plane: 1024 float4, 4 per thread; data col d at LDS offset d+4
    #pragma unroll
    for (int i = 0; i < 4; ++i) {
        int idx = i * 256 + t;          // float4 index 0..1023
        int r   = idx >> 4;
        int c4  = idx & 15;
        float4 v = ((const float4*)xp)[idx];
        *(float4*)&xs[r * XS + 4 + c4 * 4] = v;
    }
    // zero the 12 pad floats per row (4 left, 8 right): 768 total, 3/thread
    #pragma unroll
    for (int i = 0; i < 3; ++i) {
        int idx = i * 256 + t;          // 0..767
        int r   = idx / 12;
        int p   = idx % 12;
        int col = (p < 4) ? p : (p + 64);
        xs[r * XS + col] = 0.0f;
    }

    // weights once into VGPRs (block-uniform, L1-broadcast)
    float wgt[49];
    const float* wp = dw_w + c * 49;
    #pragma unroll
    for (int j = 0; j < 49; ++j) wgt[j] = wp[j];
    const float bias = dw_b[c];

    __syncthreads();

    const int h  = t >> 2;
    const int w0 = (t & 3) << 4;

    float acc[16];
    #pragma unroll
    for (int j = 0; j < 16; ++j) acc[j] = bias;

    #pragma unroll
    for (int kh = 0; kh < 7; ++kh) {
        int hh = h + kh - 3;
        if (hh < 0 || hh >= HH) continue;
        float r[24];
        const float* row = &xs[hh * XS + w0];   // LDS offset w0 <-> data col w0-4
        #pragma unroll
        for (int j = 0; j < 6; ++j) *(float4*)&r[j * 4] = *(const float4*)&row[j * 4];
        #pragma unroll
        for (int kw = 0; kw < 7; ++kw)
            #pragma unroll
            for (int j = 0; j < 16; ++j)
                acc[j] = fmaf(r[j + kw + 1], wgt[kh * 7 + kw], acc[j]);
    }

    // write 16 bf16 (32 B) coalesced, NCHW
    union { uint4 q[2]; __hip_bfloat16 b[16]; } pk;
    #pragma unroll
    for (int j = 0; j < 16; ++j) pk.b[j] = __float2bfloat16(acc[j]);
    __hip_bfloat16* op = cout + (((size_t)(n * CCH + c)) << 12) + (h << 6) + w0;
    *(uint4*)op       = pk.q[0];
    *(uint4*)(op + 8) = pk.q[1];
}

// ---------------------------------------------------------------------------
// K2: LayerNorm (from conv_out NCHW bf16) + pointwise MLP (bf16 MFMA)
//     + bias + residual, NCHW fp32 output
// one block per 64-row M tile (= one (n,h) row, w = 0..63)
// ---------------------------------------------------------------------------
#define YS 136   // bf16 row stride for sY/sH (272 B: 16B-aligned)
#define OS 65    // float row stride for sO

__global__ __launch_bounds__(256) void mlp_kernel(
    const __hip_bfloat16* __restrict__ conv,  // NCHW bf16 conv output
    const float* __restrict__ gamma,          // 128
    const float* __restrict__ beta,           // 128
    const __hip_bfloat16* __restrict__ w1,    // 512 x 128 (bf16)
    const float* __restrict__ b1,             // 512
    const __hip_bfloat16* __restrict__ w2,    // 128 x 512 (bf16)
    const float* __restrict__ b2,             // 128
    const float* __restrict__ x,              // NCHW fp32
    float* __restrict__ out)                  // NCHW fp32
{
    __shared__ union {
        struct { unsigned short y[64 * YS]; unsigned short h[64 * YS]; } s;
        float o[CCH * OS];
    } u;
    __shared__ float sPart[2][4 * 64];
    __shared__ float sMu[64], sRstd[64];

    const int t    = threadIdx.x;
    const int wave = t >> 6;
    const int lane = t & 63;
    const int q    = lane >> 4;          // 0..3
    const int ln   = lane & 15;          // 0..15
    const int wm   = (wave >> 1) * 32;   // wave M offset (0/32)
    const int wn   = (wave & 1) * 64;    // wave N offset (0/64)

    const int n = blockIdx.x >> 6;
    const int h = blockIdx.x & 63;

    // ---- LN staging: conv[n,:,h,:] -> normalized bf16 sY[w][c] ----
    {
        const int wI = t & 63;
        const int cg = t >> 6;
        const __hip_bfloat16* crow = conv + ((size_t)n << 19) + (h << 6);
        float vals[32];
        float s = 0.f, s2 = 0.f;
        #pragma unroll
        for (int j = 0; j < 32; ++j) {
            int c = cg * 32 + j;
            float v = __bfloat162float(crow[((size_t)c << 12) + wI]);
            vals[j] = v;
            s += v;
            s2 = fmaf(v, v, s2);
        }
        sPart[0][cg * 64 + wI] = s;
        sPart[1][cg * 64 + wI] = s2;
        __syncthreads();
        if (t < 64) {
            float su = 0.f, sq = 0.f;
            #pragma unroll
            for (int g = 0; g < 4; ++g) { su += sPart[0][g * 64 + t]; sq += sPart[1][g * 64 + t]; }
            float mu  = su * (1.0f / 128.0f);
            float var = sq * (1.0f / 128.0f) - mu * mu;
            sMu[t]   = mu;
            sRstd[t] = 1.0f / sqrtf(var + EPS_LN);
        }
        __syncthreads();
        float mu = sMu[wI], rs = sRstd[wI];
        #pragma unroll
        for (int j = 0; j < 32; ++j) {
            int c = cg * 32 + j;
            float r = (vals[j] - mu) * rs * gamma[c] + beta[c];
            __hip_bfloat16 hb = __float2bfloat16(r);
            u.s.y[wI * YS + c] = *(unsigned short*)&hb;
        }
    }

    f32x4 oacc[2][4];
    #pragma unroll
    for (int mt = 0; mt < 2; ++mt)
        #pragma unroll
        for (int ct = 0; ct < 4; ++ct) oacc[mt][ct] = (f32x4){0.f, 0.f, 0.f, 0.f};

    __syncthreads();

    for (int dc = 0; dc < 4; ++dc) {
        const int d0 = dc * 128;
        f32x4 hacc[2][4];
        #pragma unroll
        for (int mt = 0; mt < 2; ++mt)
            #pragma unroll
            for (int dt = 0; dt < 4; ++dt) hacc[mt][dt] = (f32x4){0.f, 0.f, 0.f, 0.f};

        // stage 1: H = y @ W1^T for this 128-wide d chunk
        #pragma unroll
        for (int k0 = 0; k0 < 128; k0 += 32) {
            bf16x8 af[2];
            #pragma unroll
            for (int mt = 0; mt < 2; ++mt)
                af[mt] = *(const bf16x8*)&u.s.y[(wm + mt * 16 + ln) * YS + k0 + q * 8];
            bf16x8 bw[4];
            #pragma unroll
            for (int dt = 0; dt < 4; ++dt) {
                int d = d0 + wn + dt * 16 + ln;
                bw[dt] = *(const bf16x8*)(w1 + (size_t)d * 128 + k0 + q * 8);
            }
            #pragma unroll
            for (int mt = 0; mt < 2; ++mt)
                #pragma unroll
                for (int dt = 0; dt < 4; ++dt)
                    hacc[mt][dt] = __builtin_amdgcn_mfma_f32_16x16x32_bf16(
                        af[mt], bw[dt], hacc[mt][dt], 0, 0, 0);
        }

        __syncthreads();   // previous chunk's sH readers done before overwrite

        // bias + relu + bf16 -> sH (C-layout scatter)
        #pragma unroll
        for (int mt = 0; mt < 2; ++mt) {
            #pragma unroll
            for (int dt = 0; dt < 4; ++dt) {
                int dl = wn + dt * 16 + ln;
                float bv = b1[d0 + dl];
                #pragma unroll
                for (int r = 0; r < 4; ++r) {
                    float v = hacc[mt][dt][r] + bv;
                    v = fmaxf(v, 0.0f);
                    __hip_bfloat16 hb = __float2bfloat16(v);
                    u.s.h[(wm + mt * 16 + q * 4 + r) * YS + dl] = *(unsigned short*)&hb;
                }
            }
        }
        __syncthreads();

        // stage 2: O += H @ W2_chunk^T
        #pragma unroll
        for (int k0 = 0; k0 < 128; k0 += 32) {
            bf16x8 af[2];
            #pragma unroll
            for (int mt = 0; mt < 2; ++mt)
                af[mt] = *(const bf16x8*)&u.s.h[(wm + mt * 16 + ln) * YS + k0 + q * 8];
            bf16x8 bw[4];
            #pragma unroll
            for (int ct = 0; ct < 4; ++ct) {
                int c = wn + ct * 16 + ln;
                bw[ct] = *(const bf16x8*)(w2 + (size_t)c * DBOT + d0 + k0 + q * 8);
            }
            #pragma unroll
            for (int mt = 0; mt < 2; ++mt)
                #pragma unroll
                for (int ct = 0; ct < 4; ++ct)
                    oacc[mt][ct] = __builtin_amdgcn_mfma_f32_16x16x32_bf16(
                        af[mt], bw[ct], oacc[mt][ct], 0, 0, 0);
        }
    }

    __syncthreads();   // union reuse: sY/sH dead, sO live

    // O (C-layout regs) -> sO[c][w]
    #pragma unroll
    for (int mt = 0; mt < 2; ++mt) {
        #pragma unroll
        for (int ct = 0; ct < 4; ++ct) {
            int c = wn + ct * 16 + ln;
            #pragma unroll
            for (int r = 0; r < 4; ++r)
                u.o[c * OS + wm + mt * 16 + q * 4 + r] = oacc[mt][ct][r];
        }
    }
    __syncthreads();

    // epilogue: out[n,c,h,:] = sO + b2[c] + x[n,c,h,:]
    const float* xb = x   + ((size_t)(n * CCH) << 12) + (h << 6);
    float*       ob = out + ((size_t)(n * CCH) << 12) + (h << 6);
    for (int i = 0; i < 32; ++i) {
        int linear = i * 256 + t;
        int c  = linear >> 6;
        int wi = linear & 63;
        float v = u.o[c * OS + wi] + b2[c] + xb[(size_t)c * 4096 + wi];
        ob[(size_t)c * 4096 + wi] = v;
    }
}

// ---------------------------------------------------------------------------
extern "C" void kernel_launch(void* const* d_in, const int* in_sizes, int n_in,
                              void* d_out, int out_size, void* d_ws, size_t ws_size,
                              hipStream_t stream)
{
    const float* x     = (const float*)d_in[0];
    const float* dw_w  = (const float*)d_in[1];
    const float* dw_b  = (const float*)d_in[2];
    const float* gamma = (const float*)d_in[3];
    const float* beta  = (const float*)d_in[4];
    const float* pw1_w = (const float*)d_in[5];
    const float* pw1_b = (const float*)d_in[6];
    const float* pw2_w = (const float*)d_in[7];
    const float* pw2_b = (const float*)d_in[8];
    float* out = (float*)d_out;

    char* ws = (char*)d_ws;
    __hip_bfloat16* convb = (__hip_bfloat16*)ws;                       // 32 MiB
    __hip_bfloat16* w1b   = (__hip_bfloat16*)(ws + (size_t)33554432);  // 128 KiB
    __hip_bfloat16* w2b   = (__hip_bfloat16*)(ws + (size_t)33554432 + 131072);

    wcvt_kernel<<<256, 256, 0, stream>>>(pw1_w, pw2_w, w1b, w2b);
    dwconv_kernel<<<NB * CCH, 256, 0, stream>>>(x, dw_w, dw_b, convb);
    mlp_kernel<<<NB * HH, 256, 0, stream>>>(convb, gamma, beta, w1b, pw1_b, w2b, pw2_b, x, out);
}

// Round 3
// 284.742 us; speedup vs baseline: 1.8515x; 1.0398x over previous
//
#include <hip/hip_runtime.h>
#include <hip/hip_bf16.h>

// Problem constants
#define NB   32
#define CCH  128
#define HH   64
#define WW   64
#define DBOT 512
#define EPS_LN 1e-5f

typedef __attribute__((ext_vector_type(8))) short bf16x8;
typedef __attribute__((ext_vector_type(4))) float f32x4;

__device__ __forceinline__ float bf2f(unsigned short u) {
    return __uint_as_float(((unsigned)u) << 16);
}
__device__ __forceinline__ unsigned short f2bf(float f) {
    __hip_bfloat16 h = __float2bfloat16(f);
    return *(unsigned short*)&h;
}

// ---------------------------------------------------------------------------
// K0: convert pointwise weights fp32 -> bf16 into workspace
// ---------------------------------------------------------------------------
__global__ __launch_bounds__(256) void wcvt_kernel(
    const float* __restrict__ w1, const float* __restrict__ w2,
    __hip_bfloat16* __restrict__ o1, __hip_bfloat16* __restrict__ o2)
{
    int i = blockIdx.x * 256 + threadIdx.x;   // 0 .. 65535
    o1[i] = __float2bfloat16(w1[i]);
    o2[i] = __float2bfloat16(w2[i]);
}

// ---------------------------------------------------------------------------
// K1: depthwise 7x7 conv + bias -> conv_out ([n][h][c][w], bf16)
// one block per (n, c) plane: 64x64 outputs, 256 threads x 16 outputs
// ---------------------------------------------------------------------------
#define XS 76   // LDS row stride (floats): 4 left pad + 64 data + 8 right pad

__global__ __launch_bounds__(256) void dwconv_kernel(
    const float* __restrict__ x, const float* __restrict__ dw_w,
    const float* __restrict__ dw_b, unsigned short* __restrict__ cout)
{
    __shared__ float xs[64 * XS];

    const int t = threadIdx.x;
    const int n = blockIdx.x >> 7;
    const int c = blockIdx.x & 127;

    const float* xp = x + ((size_t)(n * CCH + c) << 12);

    #pragma unroll
    for (int i = 0; i < 4; ++i) {
        int idx = i * 256 + t;          // float4 index 0..1023
        int r   = idx >> 4;
        int c4  = idx & 15;
        float4 v = ((const float4*)xp)[idx];
        *(float4*)&xs[r * XS + 4 + c4 * 4] = v;
    }
    #pragma unroll
    for (int i = 0; i < 3; ++i) {
        int idx = i * 256 + t;          // 0..767 pad zeroing
        int r   = idx / 12;
        int p   = idx % 12;
        int col = (p < 4) ? p : (p + 64);
        xs[r * XS + col] = 0.0f;
    }

    float wgt[49];
    const float* wp = dw_w + c * 49;
    #pragma unroll
    for (int j = 0; j < 49; ++j) wgt[j] = wp[j];
    const float bias = dw_b[c];

    __syncthreads();

    const int h  = t >> 2;
    const int w0 = (t & 3) << 4;

    float acc[16];
    #pragma unroll
    for (int j = 0; j < 16; ++j) acc[j] = bias;

    #pragma unroll
    for (int kh = 0; kh < 7; ++kh) {
        int hh = h + kh - 3;
        if (hh < 0 || hh >= HH) continue;
        float r[24];
        const float* row = &xs[hh * XS + w0];
        #pragma unroll
        for (int j = 0; j < 6; ++j) *(float4*)&r[j * 4] = *(const float4*)&row[j * 4];
        #pragma unroll
        for (int kw = 0; kw < 7; ++kw)
            #pragma unroll
            for (int j = 0; j < 16; ++j)
                acc[j] = fmaf(r[j + kw + 1], wgt[kh * 7 + kw], acc[j]);
    }

    // pack 16 bf16 into two uint4 without a private union (SROA-safe)
    uint4 s0, s1;
    {
        __hip_bfloat162 p0 = __float22bfloat162_rn(make_float2(acc[0],  acc[1]));
        __hip_bfloat162 p1 = __float22bfloat162_rn(make_float2(acc[2],  acc[3]));
        __hip_bfloat162 p2 = __float22bfloat162_rn(make_float2(acc[4],  acc[5]));
        __hip_bfloat162 p3 = __float22bfloat162_rn(make_float2(acc[6],  acc[7]));
        __hip_bfloat162 p4 = __float22bfloat162_rn(make_float2(acc[8],  acc[9]));
        __hip_bfloat162 p5 = __float22bfloat162_rn(make_float2(acc[10], acc[11]));
        __hip_bfloat162 p6 = __float22bfloat162_rn(make_float2(acc[12], acc[13]));
        __hip_bfloat162 p7 = __float22bfloat162_rn(make_float2(acc[14], acc[15]));
        s0.x = *(unsigned*)&p0; s0.y = *(unsigned*)&p1;
        s0.z = *(unsigned*)&p2; s0.w = *(unsigned*)&p3;
        s1.x = *(unsigned*)&p4; s1.y = *(unsigned*)&p5;
        s1.z = *(unsigned*)&p6; s1.w = *(unsigned*)&p7;
    }
    // layout [n][h][c][w]
    unsigned short* op = cout + ((size_t)((n * 64 + h) * 128 + c) << 6) + w0;
    *(uint4*)op       = s0;
    *(uint4*)(op + 8) = s1;
}

// ---------------------------------------------------------------------------
// K2: LayerNorm + pointwise MLP (bf16 MFMA) + bias + residual, NCHW fp32 out
// one block per (n,h) row: M = 64 positions (w), K = C = 128
// A-fragments (normalized Y) cached in VGPRs across all 4 d-chunks.
// ---------------------------------------------------------------------------
#define HS 136   // sH row stride in shorts (272 B = 17 x 16 B)

__global__ __launch_bounds__(256, 4) void mlp_kernel(
    const unsigned short* __restrict__ conv,  // [n][h][c][w] bf16
    const float* __restrict__ gamma,          // 128
    const float* __restrict__ beta,           // 128
    const __hip_bfloat16* __restrict__ w1,    // 512 x 128 (bf16)
    const float* __restrict__ b1,             // 512
    const __hip_bfloat16* __restrict__ w2,    // 128 x 512 (bf16)
    const float* __restrict__ b2,             // 128
    const float* __restrict__ x,              // NCHW fp32
    float* __restrict__ out)                  // NCHW fp32
{
    __shared__ union {
        unsigned short xs[CCH * 64];   // staged [c][w] plane (16 KB)
        unsigned short h[64 * HS];     // H chunk [pos][d] (17 KB)
    } u;
    __shared__ float sPart[2][256];
    __shared__ float sMu[64], sRstd[64];

    const int t    = threadIdx.x;
    const int wave = t >> 6;
    const int lane = t & 63;
    const int q    = lane >> 4;          // 0..3
    const int ln   = lane & 15;          // 0..15
    const int wm   = (wave >> 1) * 32;   // wave M offset (0/32)
    const int wn   = (wave & 1) * 64;    // wave N offset (0/64)

    const int n = blockIdx.x >> 6;
    const int h = blockIdx.x & 63;

    // ---- stage plane [c][w] (16 KB contiguous) into LDS ----
    {
        const uint4* src = (const uint4*)(conv + ((size_t)blockIdx.x << 13));
        #pragma unroll
        for (int i = 0; i < 4; ++i) {
            int idx = i * 256 + t;                  // 16B chunk 0..1023
            uint4 v = src[idx];
            *(uint4*)&u.xs[idx * 8] = v;
        }
    }
    __syncthreads();

    // ---- LN stats: thread (cg = t>>6, w = t&63) ----
    {
        const int wI = t & 63, cg = t >> 6;
        float s = 0.f, s2 = 0.f;
        #pragma unroll
        for (int j = 0; j < 32; ++j) {
            float v = bf2f(u.xs[(cg * 32 + j) * 64 + wI]);
            s += v;
            s2 = fmaf(v, v, s2);
        }
        sPart[0][cg * 64 + wI] = s;
        sPart[1][cg * 64 + wI] = s2;
    }
    __syncthreads();
    if (t < 64) {
        float su = 0.f, sq = 0.f;
        #pragma unroll
        for (int g = 0; g < 4; ++g) { su += sPart[0][g * 64 + t]; sq += sPart[1][g * 64 + t]; }
        float mu  = su * (1.0f / 128.0f);
        float var = sq * (1.0f / 128.0f) - mu * mu;
        sMu[t]   = mu;
        sRstd[t] = 1.0f / sqrtf(var + EPS_LN);
    }
    __syncthreads();

    // ---- build normalized A-fragments in registers: A[m=pos][k=c] ----
    bf16x8 af[2][4];
    #pragma unroll
    for (int mt = 0; mt < 2; ++mt) {
        const int pos = wm + mt * 16 + ln;
        const float mu = sMu[pos], rs = sRstd[pos];
        #pragma unroll
        for (int kb = 0; kb < 4; ++kb) {
            const int c0 = kb * 32 + q * 8;
            float4 g0  = *(const float4*)(gamma + c0);
            float4 g1  = *(const float4*)(gamma + c0 + 4);
            float4 be0 = *(const float4*)(beta + c0);
            float4 be1 = *(const float4*)(beta + c0 + 4);
            float gv[8] = {g0.x, g0.y, g0.z, g0.w, g1.x, g1.y, g1.z, g1.w};
            float bv[8] = {be0.x, be0.y, be0.z, be0.w, be1.x, be1.y, be1.z, be1.w};
            bf16x8 a;
            #pragma unroll
            for (int j = 0; j < 8; ++j) {
                float v = bf2f(u.xs[(c0 + j) * 64 + pos]);
                float r = (v - mu) * rs * gv[j] + bv[j];
                a[j] = (short)f2bf(r);
            }
            af[mt][kb] = a;
        }
    }

    f32x4 oacc[2][4];
    #pragma unroll
    for (int mt = 0; mt < 2; ++mt)
        #pragma unroll
        for (int ct = 0; ct < 4; ++ct) oacc[mt][ct] = (f32x4){0.f, 0.f, 0.f, 0.f};

    for (int dc = 0; dc < 4; ++dc) {
        const int d0 = dc * 128;

        // stage 1: Hc = Y @ W1^T (A from regs, B from global/L2)
        f32x4 hacc[2][4];
        #pragma unroll
        for (int mt = 0; mt < 2; ++mt)
            #pragma unroll
            for (int dt = 0; dt < 4; ++dt) hacc[mt][dt] = (f32x4){0.f, 0.f, 0.f, 0.f};

        #pragma unroll
        for (int kb = 0; kb < 4; ++kb) {
            bf16x8 bw[4];
            #pragma unroll
            for (int dt = 0; dt < 4; ++dt) {
                int d = d0 + wn + dt * 16 + ln;
                bw[dt] = *(const bf16x8*)(w1 + (size_t)d * 128 + kb * 32 + q * 8);
            }
            #pragma unroll
            for (int mt = 0; mt < 2; ++mt)
                #pragma unroll
                for (int dt = 0; dt < 4; ++dt)
                    hacc[mt][dt] = __builtin_amdgcn_mfma_f32_16x16x32_bf16(
                        af[mt][kb], bw[dt], hacc[mt][dt], 0, 0, 0);
        }

        __syncthreads();   // prev readers of u (xs A-build or stage2) done

        // bias + relu + bf16 -> sH
        #pragma unroll
        for (int dt = 0; dt < 4; ++dt) {
            const int dl = wn + dt * 16 + ln;
            const float b1v = b1[d0 + dl];
            #pragma unroll
            for (int mt = 0; mt < 2; ++mt) {
                #pragma unroll
                for (int r = 0; r < 4; ++r) {
                    float v = fmaxf(hacc[mt][dt][r] + b1v, 0.0f);
                    u.h[(wm + mt * 16 + q * 4 + r) * HS + dl] = f2bf(v);
                }
            }
        }
        __syncthreads();

        // stage 2: O += H @ W2_chunk^T
        #pragma unroll
        for (int kb = 0; kb < 4; ++kb) {
            bf16x8 ah[2];
            #pragma unroll
            for (int mt = 0; mt < 2; ++mt)
                ah[mt] = *(const bf16x8*)&u.h[(wm + mt * 16 + ln) * HS + kb * 32 + q * 8];
            bf16x8 bw2[4];
            #pragma unroll
            for (int ct = 0; ct < 4; ++ct) {
                int c = wn + ct * 16 + ln;
                bw2[ct] = *(const bf16x8*)(w2 + (size_t)c * DBOT + d0 + kb * 32 + q * 8);
            }
            #pragma unroll
            for (int mt = 0; mt < 2; ++mt)
                #pragma unroll
                for (int ct = 0; ct < 4; ++ct)
                    oacc[mt][ct] = __builtin_amdgcn_mfma_f32_16x16x32_bf16(
                        ah[mt], bw2[ct], oacc[mt][ct], 0, 0, 0);
        }
    }

    // ---- epilogue: direct float4 stores, out = O + b2 + x (NCHW) ----
    #pragma unroll
    for (int ct = 0; ct < 4; ++ct) {
        const int c = wn + ct * 16 + ln;
        const float b2v = b2[c];
        #pragma unroll
        for (int mt = 0; mt < 2; ++mt) {
            size_t base = ((size_t)(n * CCH + c) << 12) + (h << 6) + wm + mt * 16 + q * 4;
            float4 xr = *(const float4*)(x + base);
            float4 o;
            o.x = oacc[mt][ct][0] + b2v + xr.x;
            o.y = oacc[mt][ct][1] + b2v + xr.y;
            o.z = oacc[mt][ct][2] + b2v + xr.z;
            o.w = oacc[mt][ct][3] + b2v + xr.w;
            *(float4*)(out + base) = o;
        }
    }
}

// ---------------------------------------------------------------------------
extern "C" void kernel_launch(void* const* d_in, const int* in_sizes, int n_in,
                              void* d_out, int out_size, void* d_ws, size_t ws_size,
                              hipStream_t stream)
{
    const float* x     = (const float*)d_in[0];
    const float* dw_w  = (const float*)d_in[1];
    const float* dw_b  = (const float*)d_in[2];
    const float* gamma = (const float*)d_in[3];
    const float* beta  = (const float*)d_in[4];
    const float* pw1_w = (const float*)d_in[5];
    const float* pw1_b = (const float*)d_in[6];
    const float* pw2_w = (const float*)d_in[7];
    const float* pw2_b = (const float*)d_in[8];
    float* out = (float*)d_out;

    char* ws = (char*)d_ws;
    unsigned short* convb = (unsigned short*)ws;                       // 32 MiB
    __hip_bfloat16* w1b   = (__hip_bfloat16*)(ws + (size_t)33554432);  // 128 KiB
    __hip_bfloat16* w2b   = (__hip_bfloat16*)(ws + (size_t)33554432 + 131072);

    wcvt_kernel<<<256, 256, 0, stream>>>(pw1_w, pw2_w, w1b, w2b);
    dwconv_kernel<<<NB * CCH, 256, 0, stream>>>(x, dw_w, dw_b, convb);
    mlp_kernel<<<NB * HH, 256, 0, stream>>>(convb, gamma, beta, w1b, pw1_b, w2b, pw2_b, x, out);
}